// Round 4
// baseline (79.356 us; speedup 1.0000x reference)
//
#include <hip/hip_runtime.h>
#include <cmath>

#define H_ 128
#define W_ 128
#define P_ (H_ * W_)
#define NTX 16
#define NTY 16
#define NTILES (NTX * NTY)
#define CAP 512
#define NSPLIT 8

struct Cam {
    float ex, ey, ez;
    float r00, r01, r02, r10, r11, r12, r20, r21, r22;
};

// cnts layout: [0..255]=tileCount, [256..511]=tileDone, [512]=globalDone
__global__ __launch_bounds__(256) void zero_all(
    unsigned long long* __restrict__ zbuf, int* __restrict__ cnts) {
    int g = blockIdx.x * 256 + threadIdx.x;
    zbuf[g] = ~0ull;                    // grid = 64 blocks -> exactly P_ entries
    if (g < 513) cnts[g] = 0;
}

__global__ __launch_bounds__(256) void prep_faces(
    const float* __restrict__ verts, const int* __restrict__ faces,
    int F, Cam cam, float4* __restrict__ rec,
    int* __restrict__ cnts, int* __restrict__ tileList) {
#pragma clang fp contract(off)
    int f = blockIdx.x * blockDim.x + threadIdx.x;
    if (f >= F) return;
    float tx[3], ty[3], tz[3];
    for (int k = 0; k < 3; ++k) {
        int vi = faces[f * 3 + k];
        float vx = verts[vi * 3 + 0];
        float vy = verts[vi * 3 + 1];
        float vz = verts[vi * 3 + 2];
        float dx = vx - cam.ex, dy = vy - cam.ey, dz = vz - cam.ez;
        tx[k] = (dx * cam.r00 + dy * cam.r01) + dz * cam.r02;
        ty[k] = (dx * cam.r10 + dy * cam.r11) + dz * cam.r12;
        tz[k] = (dx * cam.r20 + dy * cam.r21) + dz * cam.r22;
    }
    float a0 = tx[0], a1 = ty[0], b0 = tx[1], b1 = ty[1], c0 = tx[2], c1 = ty[2];
    float area = (b0 - a0) * (c1 - a1) - (b1 - a1) * (c0 - a0);
    float ab = fabsf(area);
    float sa = (ab < 1e-8f) ? 1e-8f : area;
    float valid = (ab >= 1e-8f) ? 1.0f : 0.0f;
    rec[f * 3 + 0] = make_float4(a0, a1, b0, b1);
    rec[f * 3 + 1] = make_float4(c0, c1, tz[0], tz[1]);
    rec[f * 3 + 2] = make_float4(tz[2], sa, valid, 0.0f);

    if (valid == 0.0f) return;
    // Conservative pixel bbox (expanded 1 px to absorb f32 edge rounding).
    float minx = fminf(fminf(a0, b0), c0), maxx = fmaxf(fmaxf(a0, b0), c0);
    float miny = fminf(fminf(a1, b1), c1), maxy = fmaxf(fmaxf(a1, b1), c1);
    int colmin = (int)ceilf((minx + 1.0f) * 64.0f - 0.5f) - 1;
    int colmax = (int)floorf((maxx + 1.0f) * 64.0f - 0.5f) + 1;
    int rowmin = (int)ceilf((1.0f - maxy) * 64.0f - 0.5f) - 1;
    int rowmax = (int)floorf((1.0f - miny) * 64.0f - 0.5f) + 1;
    colmin = max(colmin, 0); colmax = min(colmax, W_ - 1);
    rowmin = max(rowmin, 0); rowmax = min(rowmax, H_ - 1);
    if (colmin > colmax || rowmin > rowmax) return;
    int tx0 = colmin >> 3, tx1 = colmax >> 3;
    int ty0 = rowmin >> 3, ty1 = rowmax >> 3;
    for (int ty_ = ty0; ty_ <= ty1; ++ty_)
        for (int tx_ = tx0; tx_ <= tx1; ++tx_) {
            int t = ty_ * NTX + tx_;
            int slot = atomicAdd(&cnts[t], 1);
            if (slot < CAP) tileList[t * CAP + slot] = f;
        }
}

// Grid = NTILES*NSPLIT blocks x 64 threads. Block (t,s) tests faces s, s+8,...
// of tile t for its 64 pixels; zbuf merge via u64 atomicMin (lex (d,f) ->
// exact argmin-first semantics). Last split-block per tile shades the tile;
// last tile triggers the deterministic final reduction.
__global__ __launch_bounds__(64) void raster_shade(
    const float4* __restrict__ rec, const float* __restrict__ tex,
    const float* __restrict__ ref, const int* __restrict__ cnts_ro,
    const int* __restrict__ tileList, int* __restrict__ cnts,
    unsigned long long* __restrict__ zbuf, double* __restrict__ partials,
    float* __restrict__ out) {
#pragma clang fp contract(off)
    int bid = blockIdx.x;
    int t = bid >> 3;
    int s = bid & (NSPLIT - 1);
    int tid = threadIdx.x;
    int lx = tid & 7, ly = tid >> 3;
    int col = (t & (NTX - 1)) * 8 + lx;
    int row = (t >> 4) * 8 + ly;
    int pid = row * W_ + col;
    float px = ((col + 0.5f) / 128.0f) * 2.0f - 1.0f;
    float py = 1.0f - ((row + 0.5f) / 128.0f) * 2.0f;
    int n = min(cnts_ro[t], CAP);
    const int* list = tileList + t * CAP;
    unsigned long long best = ~0ull;
    for (int i = s; i < n; i += NSPLIT) {
        int f = list[i];
        float4 r0 = rec[f * 3 + 0];
        float4 r1 = rec[f * 3 + 1];
        float4 r2 = rec[f * 3 + 2];
        float a0 = r0.x, a1 = r0.y, b0 = r0.z, b1 = r0.w;
        float c0 = r1.x, c1 = r1.y, z0 = r1.z, z1 = r1.w;
        float z2 = r2.x, sa = r2.y, valid = r2.z;
        float w0n = (c0 - b0) * (py - b1) - (c1 - b1) * (px - b0);
        float w1n = (a0 - c0) * (py - c1) - (a1 - c1) * (px - c0);
        float w2n = (b0 - a0) * (py - a1) - (b1 - a1) * (px - a0);
        bool ins;
        if (sa > 0.0f) ins = (w0n >= 0.0f) & (w1n >= 0.0f) & (w2n >= 0.0f);
        else           ins = (w0n <= 0.0f) & (w1n <= 0.0f) & (w2n <= 0.0f);
        ins = ins && (valid != 0.0f);
        if (ins) {
            float w0 = w0n / sa, w1 = w1n / sa, w2 = w2n / sa;
            float d = (w0 * z0 + w1 * z1) + w2 * z2;   // > 0 always
            unsigned long long key =
                ((unsigned long long)__float_as_uint(d) << 32) | (unsigned)f;
            best = min(best, key);
        }
    }
    if (best != ~0ull) atomicMin(&zbuf[pid], best);
    __threadfence();
    int lastv = 0;
    if (tid == 0) lastv = (atomicAdd(&cnts[256 + t], 1) == NSPLIT - 1);
    lastv = __shfl(lastv, 0);
    if (!lastv) return;

    // ---- shade this tile (all 8 splits done; atomic read = L2-coherent) ----
    unsigned long long key = atomicOr(&zbuf[pid], 0ull);
    float bd = __uint_as_float((unsigned)(key >> 32));
    bool hit = bd < 5e9f;                 // miss -> NaN -> false
    int bestf = hit ? (int)(unsigned)(key & 0xffffffffu) : 0;
    float4 r0 = rec[bestf * 3 + 0];
    float4 r1 = rec[bestf * 3 + 1];
    float4 r2 = rec[bestf * 3 + 2];
    float a0 = r0.x, a1 = r0.y, b0 = r0.z, b1 = r0.w;
    float c0 = r1.x, c1 = r1.y, sa = r2.y;
    float u0 = ((c0 - b0) * (py - b1) - (c1 - b1) * (px - b0)) / sa;
    float u1 = ((a0 - c0) * (py - c1) - (a1 - c1) * (px - c0)) / sa;
    float u2 = ((b0 - a0) * (py - a1) - (b1 - a1) * (px - a0)) / sa;
    float w0 = fminf(fmaxf(u0, 0.0f), 1.0f);
    float w1 = fminf(fmaxf(u1, 0.0f), 1.0f);
    float w2 = fminf(fmaxf(u2, 0.0f), 1.0f);
    float ssum = ((w0 + w1) + w2) + 1e-8f;
    float n0 = w0 / ssum, n1 = w1 / ssum, n2 = w2 / ssum;
    float p0 = n0 * 3.0f, p1 = n1 * 3.0f, p2 = n2 * 3.0f;
    int l0 = (int)floorf(p0); l0 = min(max(l0, 0), 2);
    int l1 = (int)floorf(p1); l1 = min(max(l1, 0), 2);
    int l2 = (int)floorf(p2); l2 = min(max(l2, 0), 2);
    float fr0 = p0 - (float)l0;
    float fr1 = p1 - (float)l1;
    float fr2 = p2 - (float)l2;
    const float* tb = tex + (size_t)bestf * 192;
    float cr = 0.0f, cg = 0.0f, cb = 0.0f;
    for (int di = 0; di < 2; ++di)
        for (int dj = 0; dj < 2; ++dj)
            for (int dk = 0; dk < 2; ++dk) {
                float wx = di ? fr0 : (1.0f - fr0);
                float wy = dj ? fr1 : (1.0f - fr1);
                float wz = dk ? fr2 : (1.0f - fr2);
                float wgt = (wx * wy) * wz;
                int off = (((l0 + di) * 4 + (l1 + dj)) * 4 + (l2 + dk)) * 3;
                cr = cr + wgt * tanhf(tb[off + 0]);
                cg = cg + wgt * tanhf(tb[off + 1]);
                cb = cb + wgt * tanhf(tb[off + 2]);
            }
    double acc = 0.0;
    {
        float fc = hit ? cr : 0.0f;
        float d = fc - ref[0 * P_ + pid];
        acc += (double)(d * d);
        fc = hit ? cg : 0.0f;
        d = fc - ref[1 * P_ + pid];
        acc += (double)(d * d);
        fc = hit ? cb : 0.0f;
        d = fc - ref[2 * P_ + pid];
        acc += (double)(d * d);
    }
    for (int off = 32; off > 0; off >>= 1) acc += __shfl_down(acc, off);
    if (tid == 0) partials[t] = acc;
    __threadfence();
    int gl = 0;
    if (tid == 0) gl = (atomicAdd(&cnts[512], 1) == NTILES - 1);
    gl = __shfl(gl, 0);
    if (!gl) return;

    // ---- final deterministic reduction (wave-parallel) ----
    double ss = 0.0;
    for (int k = 0; k < 4; ++k)
        ss += atomicAdd(&partials[tid * 4 + k], 0.0);   // coherent read
    for (int off = 32; off > 0; off >>= 1) ss += __shfl_xor(ss, off);
    if (tid == 0) out[0] = (float)ss;
}

extern "C" void kernel_launch(void* const* d_in, const int* in_sizes, int n_in,
                              void* d_out, int out_size, void* d_ws, size_t ws_size,
                              hipStream_t stream) {
    const float* vertices = (const float*)d_in[0];
    const float* textures = (const float*)d_in[1];
    const float* image_ref = (const float*)d_in[2];
    const int* faces = (const int*)d_in[3];
    int F = in_sizes[3] / 3;

    // Camera computed on host in f32, mirroring reference _look_at exactly.
    float az = (float)(90.0 * M_PI / 180.0);
    float el = 0.0f;
    float ce = cosf(el), se = sinf(el);
    float sz = sinf(az), cz = cosf(az);
    const float DIST = 2.732f;
    float ex = DIST * (ce * sz);
    float ey = DIST * se;
    float ez = DIST * (-(ce * cz));
    float nrm = sqrtf((ex * ex + ey * ey) + ez * ez);
    float z0 = -ex / nrm, z1 = -ey / nrm, z2 = -ez / nrm;
    float x0 = 1.0f * z2 - 0.0f * z1;
    float x1 = 0.0f * z0 - 0.0f * z2;
    float x2 = 0.0f * z1 - 1.0f * z0;
    float xn = sqrtf((x0 * x0 + x1 * x1) + x2 * x2);
    x0 /= xn; x1 /= xn; x2 /= xn;
    float y0 = z1 * x2 - z2 * x1;
    float y1 = z2 * x0 - z0 * x2;
    float y2 = z0 * x1 - z1 * x0;
    Cam cam{ex, ey, ez, x0, x1, x2, y0, y1, y2, z0, z1, z2};

    // Workspace: rec | cnts(513) | tileList | zbuf | partials
    size_t recB = ((size_t)F * 48 + 255) & ~(size_t)255;
    size_t cntB = (513 * sizeof(int) + 255) & ~(size_t)255;
    size_t lstB = ((size_t)NTILES * CAP * sizeof(int) + 255) & ~(size_t)255;
    size_t zbB  = ((size_t)P_ * 8 + 255) & ~(size_t)255;
    float4* rec = (float4*)d_ws;
    int* cnts = (int*)((char*)d_ws + recB);
    int* tileList = (int*)((char*)d_ws + recB + cntB);
    unsigned long long* zbuf =
        (unsigned long long*)((char*)d_ws + recB + cntB + lstB);
    double* partials = (double*)((char*)d_ws + recB + cntB + lstB + zbB);

    hipLaunchKernelGGL(zero_all, dim3(P_ / 256), dim3(256), 0, stream, zbuf, cnts);
    hipLaunchKernelGGL(prep_faces, dim3((F + 255) / 256), dim3(256), 0, stream,
                       vertices, faces, F, cam, rec, cnts, tileList);
    hipLaunchKernelGGL(raster_shade, dim3(NTILES * NSPLIT), dim3(64), 0, stream,
                       rec, textures, image_ref, cnts, tileList, cnts,
                       zbuf, partials, (float*)d_out);
}

// Round 5
// 37.071 us; speedup vs baseline: 2.1406x; 2.1406x over previous
//
#include <hip/hip_runtime.h>
#include <cmath>

#define H_ 128
#define W_ 128
#define P_ (H_ * W_)
#define NTX 16
#define NTY 16
#define NTILES (NTX * NTY)
#define CAP 512

struct Cam {
    float ex, ey, ez;
    float r00, r01, r02, r10, r11, r12, r20, r21, r22;
};

__global__ __launch_bounds__(256) void zero_cnts(int* __restrict__ cnts) {
    cnts[threadIdx.x] = 0;
}

__global__ __launch_bounds__(256) void prep_faces(
    const float* __restrict__ verts, const int* __restrict__ faces,
    int F, Cam cam, float4* __restrict__ rec,
    int* __restrict__ cnts, int* __restrict__ tileList) {
#pragma clang fp contract(off)
    int f = blockIdx.x * blockDim.x + threadIdx.x;
    if (f >= F) return;
    float tx[3], ty[3], tz[3];
    for (int k = 0; k < 3; ++k) {
        int vi = faces[f * 3 + k];
        float vx = verts[vi * 3 + 0];
        float vy = verts[vi * 3 + 1];
        float vz = verts[vi * 3 + 2];
        float dx = vx - cam.ex, dy = vy - cam.ey, dz = vz - cam.ez;
        tx[k] = (dx * cam.r00 + dy * cam.r01) + dz * cam.r02;
        ty[k] = (dx * cam.r10 + dy * cam.r11) + dz * cam.r12;
        tz[k] = (dx * cam.r20 + dy * cam.r21) + dz * cam.r22;
    }
    float a0 = tx[0], a1 = ty[0], b0 = tx[1], b1 = ty[1], c0 = tx[2], c1 = ty[2];
    float area = (b0 - a0) * (c1 - a1) - (b1 - a1) * (c0 - a0);
    float ab = fabsf(area);
    float sa = (ab < 1e-8f) ? 1e-8f : area;
    float valid = (ab >= 1e-8f) ? 1.0f : 0.0f;
    rec[f * 3 + 0] = make_float4(a0, a1, b0, b1);
    rec[f * 3 + 1] = make_float4(c0, c1, tz[0], tz[1]);
    rec[f * 3 + 2] = make_float4(tz[2], sa, valid, 0.0f);

    if (valid == 0.0f) return;
    // Conservative pixel bbox (expanded 1 px to absorb f32 edge rounding).
    float minx = fminf(fminf(a0, b0), c0), maxx = fmaxf(fmaxf(a0, b0), c0);
    float miny = fminf(fminf(a1, b1), c1), maxy = fmaxf(fmaxf(a1, b1), c1);
    int colmin = (int)ceilf((minx + 1.0f) * 64.0f - 0.5f) - 1;
    int colmax = (int)floorf((maxx + 1.0f) * 64.0f - 0.5f) + 1;
    int rowmin = (int)ceilf((1.0f - maxy) * 64.0f - 0.5f) - 1;
    int rowmax = (int)floorf((1.0f - miny) * 64.0f - 0.5f) + 1;
    colmin = max(colmin, 0); colmax = min(colmax, W_ - 1);
    rowmin = max(rowmin, 0); rowmax = min(rowmax, H_ - 1);
    if (colmin > colmax || rowmin > rowmax) return;
    int tx0 = colmin >> 3, tx1 = colmax >> 3;
    int ty0 = rowmin >> 3, ty1 = rowmax >> 3;
    for (int ty_ = ty0; ty_ <= ty1; ++ty_)
        for (int tx_ = tx0; tx_ <= tx1; ++tx_) {
            int t = ty_ * NTX + tx_;
            int slot = atomicAdd(&cnts[t], 1);
            if (slot < CAP) tileList[t * CAP + slot] = f;
        }
}

// Grid = NTILES << shift blocks x 64 threads. Block (t,s) tests faces
// s, s+nsplit, ... of tile t for its 64 pixels and writes its best
// (depth,face) key per pixel NON-atomically to its own sbuf plane.
// Key = (f32 bits of depth << 32) | f  -- depth > 0 always, so u64 order
// == lexicographic (depth, face) == jnp.argmin first-index semantics.
__global__ __launch_bounds__(64) void raster(
    const float4* __restrict__ rec, const int* __restrict__ cnts,
    const int* __restrict__ tileList, unsigned long long* __restrict__ sbuf,
    int shift) {
#pragma clang fp contract(off)
    int bid = blockIdx.x;
    int nsplit = 1 << shift;
    int t = bid >> shift;
    int s = bid & (nsplit - 1);
    int tid = threadIdx.x;
    int lx = tid & 7, ly = tid >> 3;
    int col = (t & (NTX - 1)) * 8 + lx;
    int row = (t >> 4) * 8 + ly;
    int pid = row * W_ + col;
    float px = ((col + 0.5f) / 128.0f) * 2.0f - 1.0f;
    float py = 1.0f - ((row + 0.5f) / 128.0f) * 2.0f;
    int n = min(cnts[t], CAP);
    const int* list = tileList + t * CAP;
    unsigned long long best = ~0ull;
    for (int i = s; i < n; i += nsplit) {
        int f = list[i];
        float4 r0 = rec[f * 3 + 0];
        float4 r1 = rec[f * 3 + 1];
        float4 r2 = rec[f * 3 + 2];
        float a0 = r0.x, a1 = r0.y, b0 = r0.z, b1 = r0.w;
        float c0 = r1.x, c1 = r1.y, z0 = r1.z, z1 = r1.w;
        float z2 = r2.x, sa = r2.y;
        float w0n = (c0 - b0) * (py - b1) - (c1 - b1) * (px - b0);
        float w1n = (a0 - c0) * (py - c1) - (a1 - c1) * (px - c0);
        float w2n = (b0 - a0) * (py - a1) - (b1 - a1) * (px - a0);
        bool ins;
        if (sa > 0.0f) ins = (w0n >= 0.0f) & (w1n >= 0.0f) & (w2n >= 0.0f);
        else           ins = (w0n <= 0.0f) & (w1n <= 0.0f) & (w2n <= 0.0f);
        if (ins) {
            float w0 = w0n / sa, w1 = w1n / sa, w2 = w2n / sa;
            float d = (w0 * z0 + w1 * z1) + w2 * z2;   // always > 0 here
            unsigned long long key =
                ((unsigned long long)__float_as_uint(d) << 32) | (unsigned)f;
            best = min(best, key);
        }
    }
    sbuf[(size_t)s * P_ + pid] = best;
}

// 64 blocks x 256 threads: merge split keys, shade, per-block reduce.
__global__ __launch_bounds__(256) void shade(
    const float4* __restrict__ rec, const float* __restrict__ tex,
    const float* __restrict__ ref, const unsigned long long* __restrict__ sbuf,
    int nsplit, double* __restrict__ partials) {
#pragma clang fp contract(off)
    int pid = blockIdx.x * 256 + threadIdx.x;
    int row = pid >> 7, col = pid & 127;
    float px = ((col + 0.5f) / 128.0f) * 2.0f - 1.0f;
    float py = 1.0f - ((row + 0.5f) / 128.0f) * 2.0f;
    unsigned long long key = ~0ull;
    for (int s = 0; s < nsplit; ++s)
        key = min(key, sbuf[(size_t)s * P_ + pid]);
    float bd = __uint_as_float((unsigned)(key >> 32));
    bool hit = bd < 5e9f;                  // miss -> NaN bits -> false
    int bestf = hit ? (int)(unsigned)(key & 0xffffffffu) : 0;
    float4 r0 = rec[bestf * 3 + 0];
    float4 r1 = rec[bestf * 3 + 1];
    float4 r2 = rec[bestf * 3 + 2];
    float a0 = r0.x, a1 = r0.y, b0 = r0.z, b1 = r0.w;
    float c0 = r1.x, c1 = r1.y, sa = r2.y;
    float u0 = ((c0 - b0) * (py - b1) - (c1 - b1) * (px - b0)) / sa;
    float u1 = ((a0 - c0) * (py - c1) - (a1 - c1) * (px - c0)) / sa;
    float u2 = ((b0 - a0) * (py - a1) - (b1 - a1) * (px - a0)) / sa;
    float w0 = fminf(fmaxf(u0, 0.0f), 1.0f);
    float w1 = fminf(fmaxf(u1, 0.0f), 1.0f);
    float w2 = fminf(fmaxf(u2, 0.0f), 1.0f);
    float ssum = ((w0 + w1) + w2) + 1e-8f;
    float n0 = w0 / ssum, n1 = w1 / ssum, n2 = w2 / ssum;
    float p0 = n0 * 3.0f, p1 = n1 * 3.0f, p2 = n2 * 3.0f;
    int l0 = (int)floorf(p0); l0 = min(max(l0, 0), 2);
    int l1 = (int)floorf(p1); l1 = min(max(l1, 0), 2);
    int l2 = (int)floorf(p2); l2 = min(max(l2, 0), 2);
    float fr0 = p0 - (float)l0;
    float fr1 = p1 - (float)l1;
    float fr2 = p2 - (float)l2;
    const float* tb = tex + (size_t)bestf * 192;
    float cr = 0.0f, cg = 0.0f, cb = 0.0f;
    for (int di = 0; di < 2; ++di)
        for (int dj = 0; dj < 2; ++dj)
            for (int dk = 0; dk < 2; ++dk) {
                float wx = di ? fr0 : (1.0f - fr0);
                float wy = dj ? fr1 : (1.0f - fr1);
                float wz = dk ? fr2 : (1.0f - fr2);
                float wgt = (wx * wy) * wz;
                int off = (((l0 + di) * 4 + (l1 + dj)) * 4 + (l2 + dk)) * 3;
                cr = cr + wgt * tanhf(tb[off + 0]);
                cg = cg + wgt * tanhf(tb[off + 1]);
                cb = cb + wgt * tanhf(tb[off + 2]);
            }
    double acc = 0.0;
    {
        float fc = hit ? cr : 0.0f;
        float d = fc - ref[0 * P_ + pid];
        acc += (double)(d * d);
        fc = hit ? cg : 0.0f;
        d = fc - ref[1 * P_ + pid];
        acc += (double)(d * d);
        fc = hit ? cb : 0.0f;
        d = fc - ref[2 * P_ + pid];
        acc += (double)(d * d);
    }
    for (int off = 32; off > 0; off >>= 1) acc += __shfl_down(acc, off);
    __shared__ double lsum[4];
    int lane = threadIdx.x & 63, wv = threadIdx.x >> 6;
    if (lane == 0) lsum[wv] = acc;
    __syncthreads();
    if (threadIdx.x == 0)
        partials[blockIdx.x] = ((lsum[0] + lsum[1]) + lsum[2]) + lsum[3];
}

__global__ __launch_bounds__(64) void finalize(
    const double* __restrict__ partials, float* __restrict__ out) {
    double v = partials[threadIdx.x];
    for (int off = 32; off > 0; off >>= 1) v += __shfl_xor(v, off);
    if (threadIdx.x == 0) out[0] = (float)v;
}

extern "C" void kernel_launch(void* const* d_in, const int* in_sizes, int n_in,
                              void* d_out, int out_size, void* d_ws, size_t ws_size,
                              hipStream_t stream) {
    const float* vertices = (const float*)d_in[0];
    const float* textures = (const float*)d_in[1];
    const float* image_ref = (const float*)d_in[2];
    const int* faces = (const int*)d_in[3];
    int F = in_sizes[3] / 3;

    // Camera computed on host in f32, mirroring reference _look_at exactly.
    float az = (float)(90.0 * M_PI / 180.0);
    float el = 0.0f;
    float ce = cosf(el), se = sinf(el);
    float sz = sinf(az), cz = cosf(az);
    const float DIST = 2.732f;
    float ex = DIST * (ce * sz);
    float ey = DIST * se;
    float ez = DIST * (-(ce * cz));
    float nrm = sqrtf((ex * ex + ey * ey) + ez * ez);
    float z0 = -ex / nrm, z1 = -ey / nrm, z2 = -ez / nrm;
    float x0 = 1.0f * z2 - 0.0f * z1;
    float x1 = 0.0f * z0 - 0.0f * z2;
    float x2 = 0.0f * z1 - 1.0f * z0;
    float xn = sqrtf((x0 * x0 + x1 * x1) + x2 * x2);
    x0 /= xn; x1 /= xn; x2 /= xn;
    float y0 = z1 * x2 - z2 * x1;
    float y1 = z2 * x0 - z0 * x2;
    float y2 = z0 * x1 - z1 * x0;
    Cam cam{ex, ey, ez, x0, x1, x2, y0, y1, y2, z0, z1, z2};

    // Workspace: rec | cnts(256) | tileList | sbuf | partials(64)
    size_t recB = ((size_t)F * 48 + 255) & ~(size_t)255;
    size_t cntB = (256 * sizeof(int) + 255) & ~(size_t)255;
    size_t lstB = ((size_t)NTILES * CAP * sizeof(int) + 255) & ~(size_t)255;
    size_t parB = 64 * sizeof(double);
    int shift = 3;
    while (shift > 0 &&
           recB + cntB + lstB + ((size_t)(1 << shift) * P_ * 8) + parB > ws_size)
        --shift;
    int nsplit = 1 << shift;
    size_t sbB = ((size_t)nsplit * P_ * 8 + 255) & ~(size_t)255;

    float4* rec = (float4*)d_ws;
    int* cnts = (int*)((char*)d_ws + recB);
    int* tileList = (int*)((char*)d_ws + recB + cntB);
    unsigned long long* sbuf =
        (unsigned long long*)((char*)d_ws + recB + cntB + lstB);
    double* partials = (double*)((char*)d_ws + recB + cntB + lstB + sbB);

    hipLaunchKernelGGL(zero_cnts, dim3(1), dim3(256), 0, stream, cnts);
    hipLaunchKernelGGL(prep_faces, dim3((F + 255) / 256), dim3(256), 0, stream,
                       vertices, faces, F, cam, rec, cnts, tileList);
    hipLaunchKernelGGL(raster, dim3(NTILES * nsplit), dim3(64), 0, stream,
                       rec, cnts, tileList, sbuf, shift);
    hipLaunchKernelGGL(shade, dim3(P_ / 256), dim3(256), 0, stream,
                       rec, textures, image_ref, sbuf, nsplit, partials);
    hipLaunchKernelGGL(finalize, dim3(1), dim3(64), 0, stream,
                       partials, (float*)d_out);
}

// Round 6
// 22.042 us; speedup vs baseline: 3.6001x; 1.6818x over previous
//
#include <hip/hip_runtime.h>
#include <cmath>

#define H_ 128
#define W_ 128
#define P_ (H_ * W_)
#define NTX 16
#define NTY 16
#define NTILES (NTX * NTY)
#define CAP 512

struct Cam {
    float ex, ey, ez;
    float r00, r01, r02, r10, r11, r12, r20, r21, r22;
};

// Per-face record (3x float4) + packed tile bbox (-1 = culled).
__global__ __launch_bounds__(256) void prep_faces(
    const float* __restrict__ verts, const int* __restrict__ faces,
    int F, Cam cam, float4* __restrict__ rec, int* __restrict__ bbox) {
#pragma clang fp contract(off)
    int f = blockIdx.x * blockDim.x + threadIdx.x;
    if (f >= F) return;
    float tx[3], ty[3], tz[3];
    for (int k = 0; k < 3; ++k) {
        int vi = faces[f * 3 + k];
        float vx = verts[vi * 3 + 0];
        float vy = verts[vi * 3 + 1];
        float vz = verts[vi * 3 + 2];
        float dx = vx - cam.ex, dy = vy - cam.ey, dz = vz - cam.ez;
        tx[k] = (dx * cam.r00 + dy * cam.r01) + dz * cam.r02;
        ty[k] = (dx * cam.r10 + dy * cam.r11) + dz * cam.r12;
        tz[k] = (dx * cam.r20 + dy * cam.r21) + dz * cam.r22;
    }
    float a0 = tx[0], a1 = ty[0], b0 = tx[1], b1 = ty[1], c0 = tx[2], c1 = ty[2];
    float area = (b0 - a0) * (c1 - a1) - (b1 - a1) * (c0 - a0);
    float ab = fabsf(area);
    float sa = (ab < 1e-8f) ? 1e-8f : area;
    float valid = (ab >= 1e-8f) ? 1.0f : 0.0f;
    rec[f * 3 + 0] = make_float4(a0, a1, b0, b1);
    rec[f * 3 + 1] = make_float4(c0, c1, tz[0], tz[1]);
    rec[f * 3 + 2] = make_float4(tz[2], sa, valid, 0.0f);

    int bb = -1;
    if (valid != 0.0f) {
        // Conservative pixel bbox (expanded 1 px to absorb f32 edge rounding).
        float minx = fminf(fminf(a0, b0), c0), maxx = fmaxf(fmaxf(a0, b0), c0);
        float miny = fminf(fminf(a1, b1), c1), maxy = fmaxf(fmaxf(a1, b1), c1);
        int colmin = (int)ceilf((minx + 1.0f) * 64.0f - 0.5f) - 1;
        int colmax = (int)floorf((maxx + 1.0f) * 64.0f - 0.5f) + 1;
        int rowmin = (int)ceilf((1.0f - maxy) * 64.0f - 0.5f) - 1;
        int rowmax = (int)floorf((1.0f - miny) * 64.0f - 0.5f) + 1;
        colmin = max(colmin, 0); colmax = min(colmax, W_ - 1);
        rowmin = max(rowmin, 0); rowmax = min(rowmax, H_ - 1);
        if (colmin <= colmax && rowmin <= rowmax) {
            bb = (colmin >> 3) | ((colmax >> 3) << 4)
               | ((rowmin >> 3) << 8) | ((rowmax >> 3) << 12);
        }
    }
    bbox[f] = bb;
}

// One 512-thread block per 8x8 tile. Build face list in LDS (bbox scan),
// stage records in LDS, 8 waves raster stride-8 slices, merge in LDS,
// wave 0 shades + reduces. Key=(depth_bits<<32)|f: u64 lex-min == exact
// jnp.argmin first-index tie-break (depth>0 always), so LDS-append order
// doesn't matter.
__global__ __launch_bounds__(512) void raster_shade(
    const float4* __restrict__ rec, const float* __restrict__ tex,
    const float* __restrict__ ref, const int* __restrict__ bbox, int F,
    double* __restrict__ partials) {
#pragma clang fp contract(off)
    __shared__ int lcnt;
    __shared__ int lfi[CAP];
    __shared__ float4 lrec[CAP * 3];
    __shared__ unsigned long long lbest[8 * 64];
    int t = blockIdx.x;
    int tid = threadIdx.x;
    int mytx = t & (NTX - 1), myty = t >> 4;
    if (tid == 0) lcnt = 0;
    __syncthreads();
    for (int f = tid; f < F; f += 512) {
        int bb = bbox[f];
        if (bb < 0) continue;
        int tx0 = bb & 15, tx1 = (bb >> 4) & 15;
        int ty0 = (bb >> 8) & 15, ty1 = (bb >> 12) & 15;
        if (mytx >= tx0 && mytx <= tx1 && myty >= ty0 && myty <= ty1) {
            int slot = atomicAdd(&lcnt, 1);
            if (slot < CAP) lfi[slot] = f;
        }
    }
    __syncthreads();
    int n = min(lcnt, CAP);
    for (int j = tid; j < n; j += 512) {
        int f = lfi[j];
        lrec[j * 3 + 0] = rec[f * 3 + 0];
        lrec[j * 3 + 1] = rec[f * 3 + 1];
        lrec[j * 3 + 2] = rec[f * 3 + 2];
    }
    __syncthreads();

    int wv = tid >> 6, lane = tid & 63;
    int lx = lane & 7, ly = lane >> 3;
    int col = mytx * 8 + lx, row = myty * 8 + ly;
    int pid = row * W_ + col;
    float px = ((col + 0.5f) / 128.0f) * 2.0f - 1.0f;
    float py = 1.0f - ((row + 0.5f) / 128.0f) * 2.0f;
    unsigned long long best = ~0ull;
    for (int i = wv; i < n; i += 8) {
        float4 r0 = lrec[i * 3 + 0];
        float4 r1 = lrec[i * 3 + 1];
        float4 r2 = lrec[i * 3 + 2];
        float a0 = r0.x, a1 = r0.y, b0 = r0.z, b1 = r0.w;
        float c0 = r1.x, c1 = r1.y, z0 = r1.z, z1 = r1.w;
        float z2 = r2.x, sa = r2.y;
        float w0n = (c0 - b0) * (py - b1) - (c1 - b1) * (px - b0);
        float w1n = (a0 - c0) * (py - c1) - (a1 - c1) * (px - c0);
        float w2n = (b0 - a0) * (py - a1) - (b1 - a1) * (px - a0);
        bool ins;
        if (sa > 0.0f) ins = (w0n >= 0.0f) & (w1n >= 0.0f) & (w2n >= 0.0f);
        else           ins = (w0n <= 0.0f) & (w1n <= 0.0f) & (w2n <= 0.0f);
        if (ins) {
            float w0 = w0n / sa, w1 = w1n / sa, w2 = w2n / sa;
            float d = (w0 * z0 + w1 * z1) + w2 * z2;   // always > 0 here
            unsigned long long key =
                ((unsigned long long)__float_as_uint(d) << 32)
                | (unsigned)lfi[i];
            best = min(best, key);
        }
    }
    lbest[wv * 64 + lane] = best;
    __syncthreads();
    if (wv != 0) return;

    unsigned long long key = best;
    for (int s = 1; s < 8; ++s) key = min(key, lbest[s * 64 + lane]);
    float bd = __uint_as_float((unsigned)(key >> 32));
    bool hit = bd < 5e9f;                  // miss -> NaN bits -> false
    int bestf = hit ? (int)(unsigned)(key & 0xffffffffu) : 0;
    float4 r0 = rec[bestf * 3 + 0];
    float4 r1 = rec[bestf * 3 + 1];
    float4 r2 = rec[bestf * 3 + 2];
    float a0 = r0.x, a1 = r0.y, b0 = r0.z, b1 = r0.w;
    float c0 = r1.x, c1 = r1.y, sa = r2.y;
    float u0 = ((c0 - b0) * (py - b1) - (c1 - b1) * (px - b0)) / sa;
    float u1 = ((a0 - c0) * (py - c1) - (a1 - c1) * (px - c0)) / sa;
    float u2 = ((b0 - a0) * (py - a1) - (b1 - a1) * (px - a0)) / sa;
    float w0 = fminf(fmaxf(u0, 0.0f), 1.0f);
    float w1 = fminf(fmaxf(u1, 0.0f), 1.0f);
    float w2 = fminf(fmaxf(u2, 0.0f), 1.0f);
    float ssum = ((w0 + w1) + w2) + 1e-8f;
    float n0 = w0 / ssum, n1 = w1 / ssum, n2 = w2 / ssum;
    float p0 = n0 * 3.0f, p1 = n1 * 3.0f, p2 = n2 * 3.0f;
    int l0 = (int)floorf(p0); l0 = min(max(l0, 0), 2);
    int l1 = (int)floorf(p1); l1 = min(max(l1, 0), 2);
    int l2 = (int)floorf(p2); l2 = min(max(l2, 0), 2);
    float fr0 = p0 - (float)l0;
    float fr1 = p1 - (float)l1;
    float fr2 = p2 - (float)l2;
    const float* tb = tex + (size_t)bestf * 192;
    float cr = 0.0f, cg = 0.0f, cb = 0.0f;
    for (int di = 0; di < 2; ++di)
        for (int dj = 0; dj < 2; ++dj)
            for (int dk = 0; dk < 2; ++dk) {
                float wx = di ? fr0 : (1.0f - fr0);
                float wy = dj ? fr1 : (1.0f - fr1);
                float wz = dk ? fr2 : (1.0f - fr2);
                float wgt = (wx * wy) * wz;
                int off = (((l0 + di) * 4 + (l1 + dj)) * 4 + (l2 + dk)) * 3;
                cr = cr + wgt * tanhf(tb[off + 0]);
                cg = cg + wgt * tanhf(tb[off + 1]);
                cb = cb + wgt * tanhf(tb[off + 2]);
            }
    double acc = 0.0;
    {
        float fc = hit ? cr : 0.0f;
        float d = fc - ref[0 * P_ + pid];
        acc += (double)(d * d);
        fc = hit ? cg : 0.0f;
        d = fc - ref[1 * P_ + pid];
        acc += (double)(d * d);
        fc = hit ? cb : 0.0f;
        d = fc - ref[2 * P_ + pid];
        acc += (double)(d * d);
    }
    for (int off = 32; off > 0; off >>= 1) acc += __shfl_down(acc, off);
    if (lane == 0) partials[t] = acc;
}

__global__ __launch_bounds__(64) void finalize(
    const double* __restrict__ partials, float* __restrict__ out) {
    double v = 0.0;
    for (int k = 0; k < 4; ++k) v += partials[threadIdx.x * 4 + k];
    for (int off = 32; off > 0; off >>= 1) v += __shfl_xor(v, off);
    if (threadIdx.x == 0) out[0] = (float)v;
}

extern "C" void kernel_launch(void* const* d_in, const int* in_sizes, int n_in,
                              void* d_out, int out_size, void* d_ws, size_t ws_size,
                              hipStream_t stream) {
    const float* vertices = (const float*)d_in[0];
    const float* textures = (const float*)d_in[1];
    const float* image_ref = (const float*)d_in[2];
    const int* faces = (const int*)d_in[3];
    int F = in_sizes[3] / 3;

    // Camera computed on host in f32, mirroring reference _look_at exactly.
    float az = (float)(90.0 * M_PI / 180.0);
    float el = 0.0f;
    float ce = cosf(el), se = sinf(el);
    float sz = sinf(az), cz = cosf(az);
    const float DIST = 2.732f;
    float ex = DIST * (ce * sz);
    float ey = DIST * se;
    float ez = DIST * (-(ce * cz));
    float nrm = sqrtf((ex * ex + ey * ey) + ez * ez);
    float z0 = -ex / nrm, z1 = -ey / nrm, z2 = -ez / nrm;
    float x0 = 1.0f * z2 - 0.0f * z1;
    float x1 = 0.0f * z0 - 0.0f * z2;
    float x2 = 0.0f * z1 - 1.0f * z0;
    float xn = sqrtf((x0 * x0 + x1 * x1) + x2 * x2);
    x0 /= xn; x1 /= xn; x2 /= xn;
    float y0 = z1 * x2 - z2 * x1;
    float y1 = z2 * x0 - z0 * x2;
    float y2 = z0 * x1 - z1 * x0;
    Cam cam{ex, ey, ez, x0, x1, x2, y0, y1, y2, z0, z1, z2};

    // Workspace: rec | bbox | partials(256)
    size_t recB = ((size_t)F * 48 + 255) & ~(size_t)255;
    size_t bbB = ((size_t)F * sizeof(int) + 255) & ~(size_t)255;
    float4* rec = (float4*)d_ws;
    int* bbox = (int*)((char*)d_ws + recB);
    double* partials = (double*)((char*)d_ws + recB + bbB);

    hipLaunchKernelGGL(prep_faces, dim3((F + 255) / 256), dim3(256), 0, stream,
                       vertices, faces, F, cam, rec, bbox);
    hipLaunchKernelGGL(raster_shade, dim3(NTILES), dim3(512), 0, stream,
                       rec, textures, image_ref, bbox, F, partials);
    hipLaunchKernelGGL(finalize, dim3(1), dim3(64), 0, stream,
                       partials, (float*)d_out);
}

// Round 7
// 18.156 us; speedup vs baseline: 4.3707x; 1.2140x over previous
//
#include <hip/hip_runtime.h>
#include <cmath>

#define H_ 128
#define W_ 128
#define P_ (H_ * W_)
#define NTX 16
#define NTY 16
#define NTILES (NTX * NTY)
#define CAP 512

struct Cam {
    float ex, ey, ez;
    float r00, r01, r02, r10, r11, r12, r20, r21, r22;
};

// One 512-thread block per 8x8 tile. Each block transforms ALL faces
// cooperatively (5/thread), culls to its tile, appends records straight
// into LDS; 8 waves raster stride-8 slices; wave 0 shades + reduces.
// Key=(depth_bits<<32)|global_f: u64 lex-min == exact jnp.argmin
// first-index tie-break (depth>0 always), so append order is irrelevant.
__global__ __launch_bounds__(512) void render_all(
    const float* __restrict__ verts, const int* __restrict__ faces, int F,
    Cam cam, const float* __restrict__ tex, const float* __restrict__ ref,
    double* __restrict__ partials) {
#pragma clang fp contract(off)
    __shared__ int lcnt;
    __shared__ int lfi[CAP];
    __shared__ float4 lrec[CAP * 3];
    __shared__ unsigned long long lbest[8 * 64];
    int t = blockIdx.x;
    int tid = threadIdx.x;
    int mytx = t & (NTX - 1), myty = t >> 4;
    if (tid == 0) lcnt = 0;
    __syncthreads();

    // ---- transform + cull + LDS append ----
    for (int f = tid; f < F; f += 512) {
        float tx[3], ty[3], tz[3];
        for (int k = 0; k < 3; ++k) {
            int vi = faces[f * 3 + k];
            float vx = verts[vi * 3 + 0];
            float vy = verts[vi * 3 + 1];
            float vz = verts[vi * 3 + 2];
            float dx = vx - cam.ex, dy = vy - cam.ey, dz = vz - cam.ez;
            tx[k] = (dx * cam.r00 + dy * cam.r01) + dz * cam.r02;
            ty[k] = (dx * cam.r10 + dy * cam.r11) + dz * cam.r12;
            tz[k] = (dx * cam.r20 + dy * cam.r21) + dz * cam.r22;
        }
        float a0 = tx[0], a1 = ty[0], b0 = tx[1], b1 = ty[1];
        float c0 = tx[2], c1 = ty[2];
        float area = (b0 - a0) * (c1 - a1) - (b1 - a1) * (c0 - a0);
        float ab = fabsf(area);
        if (ab < 1e-8f) continue;
        float sa = area;
        // Conservative pixel bbox (expanded 1 px to absorb f32 edge rounding).
        float minx = fminf(fminf(a0, b0), c0), maxx = fmaxf(fmaxf(a0, b0), c0);
        float miny = fminf(fminf(a1, b1), c1), maxy = fmaxf(fmaxf(a1, b1), c1);
        int colmin = (int)ceilf((minx + 1.0f) * 64.0f - 0.5f) - 1;
        int colmax = (int)floorf((maxx + 1.0f) * 64.0f - 0.5f) + 1;
        int rowmin = (int)ceilf((1.0f - maxy) * 64.0f - 0.5f) - 1;
        int rowmax = (int)floorf((1.0f - miny) * 64.0f - 0.5f) + 1;
        colmin = max(colmin, 0); colmax = min(colmax, W_ - 1);
        rowmin = max(rowmin, 0); rowmax = min(rowmax, H_ - 1);
        if (colmin > colmax || rowmin > rowmax) continue;
        if (mytx < (colmin >> 3) || mytx > (colmax >> 3) ||
            myty < (rowmin >> 3) || myty > (rowmax >> 3)) continue;
        int slot = atomicAdd(&lcnt, 1);
        if (slot < CAP) {
            lfi[slot] = f;
            lrec[slot * 3 + 0] = make_float4(a0, a1, b0, b1);
            lrec[slot * 3 + 1] = make_float4(c0, c1, tz[0], tz[1]);
            lrec[slot * 3 + 2] = make_float4(tz[2], sa, 0.0f, 0.0f);
        }
    }
    __syncthreads();
    int n = min(lcnt, CAP);

    // ---- raster: 8 waves, stride-8 slices of the list ----
    int wv = tid >> 6, lane = tid & 63;
    int lx = lane & 7, ly = lane >> 3;
    int col = mytx * 8 + lx, row = myty * 8 + ly;
    int pid = row * W_ + col;
    float px = ((col + 0.5f) / 128.0f) * 2.0f - 1.0f;
    float py = 1.0f - ((row + 0.5f) / 128.0f) * 2.0f;
    unsigned long long best = ~0ull;
    for (int i = wv; i < n; i += 8) {
        float4 r0 = lrec[i * 3 + 0];
        float4 r1 = lrec[i * 3 + 1];
        float4 r2 = lrec[i * 3 + 2];
        float a0 = r0.x, a1 = r0.y, b0 = r0.z, b1 = r0.w;
        float c0 = r1.x, c1 = r1.y, z0 = r1.z, z1 = r1.w;
        float z2 = r2.x, sa = r2.y;
        float w0n = (c0 - b0) * (py - b1) - (c1 - b1) * (px - b0);
        float w1n = (a0 - c0) * (py - c1) - (a1 - c1) * (px - c0);
        float w2n = (b0 - a0) * (py - a1) - (b1 - a1) * (px - a0);
        bool ins;
        if (sa > 0.0f) ins = (w0n >= 0.0f) & (w1n >= 0.0f) & (w2n >= 0.0f);
        else           ins = (w0n <= 0.0f) & (w1n <= 0.0f) & (w2n <= 0.0f);
        if (ins) {
            float w0 = w0n / sa, w1 = w1n / sa, w2 = w2n / sa;
            float d = (w0 * z0 + w1 * z1) + w2 * z2;   // always > 0 here
            unsigned long long key =
                ((unsigned long long)__float_as_uint(d) << 32)
                | (unsigned)lfi[i];
            best = min(best, key);
        }
    }
    lbest[wv * 64 + lane] = best;
    __syncthreads();
    if (wv != 0) return;

    // ---- merge + shade (wave 0 only) ----
    unsigned long long key = best;
    for (int s = 1; s < 8; ++s) key = min(key, lbest[s * 64 + lane]);
    float bd = __uint_as_float((unsigned)(key >> 32));
    bool hit = bd < 5e9f;                  // miss -> NaN bits -> false
    int bestf = hit ? (int)(unsigned)(key & 0xffffffffu) : 0;
    // Recompute winning face's 2D record (bit-identical expressions).
    float a0, a1, b0, b1, c0, c1, sa;
    {
        float tx[3], ty[3];
        for (int k = 0; k < 3; ++k) {
            int vi = faces[bestf * 3 + k];
            float vx = verts[vi * 3 + 0];
            float vy = verts[vi * 3 + 1];
            float vz = verts[vi * 3 + 2];
            float dx = vx - cam.ex, dy = vy - cam.ey, dz = vz - cam.ez;
            tx[k] = (dx * cam.r00 + dy * cam.r01) + dz * cam.r02;
            ty[k] = (dx * cam.r10 + dy * cam.r11) + dz * cam.r12;
        }
        a0 = tx[0]; a1 = ty[0]; b0 = tx[1]; b1 = ty[1]; c0 = tx[2]; c1 = ty[2];
        float area = (b0 - a0) * (c1 - a1) - (b1 - a1) * (c0 - a0);
        sa = (fabsf(area) < 1e-8f) ? 1e-8f : area;
    }
    float u0 = ((c0 - b0) * (py - b1) - (c1 - b1) * (px - b0)) / sa;
    float u1 = ((a0 - c0) * (py - c1) - (a1 - c1) * (px - c0)) / sa;
    float u2 = ((b0 - a0) * (py - a1) - (b1 - a1) * (px - a0)) / sa;
    float w0 = fminf(fmaxf(u0, 0.0f), 1.0f);
    float w1 = fminf(fmaxf(u1, 0.0f), 1.0f);
    float w2 = fminf(fmaxf(u2, 0.0f), 1.0f);
    float ssum = ((w0 + w1) + w2) + 1e-8f;
    float n0 = w0 / ssum, n1 = w1 / ssum, n2 = w2 / ssum;
    float p0 = n0 * 3.0f, p1 = n1 * 3.0f, p2 = n2 * 3.0f;
    int l0 = (int)floorf(p0); l0 = min(max(l0, 0), 2);
    int l1 = (int)floorf(p1); l1 = min(max(l1, 0), 2);
    int l2 = (int)floorf(p2); l2 = min(max(l2, 0), 2);
    float fr0 = p0 - (float)l0;
    float fr1 = p1 - (float)l1;
    float fr2 = p2 - (float)l2;
    const float* tb = tex + (size_t)bestf * 192;
    float cr = 0.0f, cg = 0.0f, cb = 0.0f;
    for (int di = 0; di < 2; ++di)
        for (int dj = 0; dj < 2; ++dj)
            for (int dk = 0; dk < 2; ++dk) {
                float wx = di ? fr0 : (1.0f - fr0);
                float wy = dj ? fr1 : (1.0f - fr1);
                float wz = dk ? fr2 : (1.0f - fr2);
                float wgt = (wx * wy) * wz;
                int off = (((l0 + di) * 4 + (l1 + dj)) * 4 + (l2 + dk)) * 3;
                cr = cr + wgt * tanhf(tb[off + 0]);
                cg = cg + wgt * tanhf(tb[off + 1]);
                cb = cb + wgt * tanhf(tb[off + 2]);
            }
    double acc = 0.0;
    {
        float fc = hit ? cr : 0.0f;
        float d = fc - ref[0 * P_ + pid];
        acc += (double)(d * d);
        fc = hit ? cg : 0.0f;
        d = fc - ref[1 * P_ + pid];
        acc += (double)(d * d);
        fc = hit ? cb : 0.0f;
        d = fc - ref[2 * P_ + pid];
        acc += (double)(d * d);
    }
    for (int off = 32; off > 0; off >>= 1) acc += __shfl_down(acc, off);
    if (lane == 0) partials[t] = acc;
}

__global__ __launch_bounds__(64) void finalize(
    const double* __restrict__ partials, float* __restrict__ out) {
    double v = 0.0;
    for (int k = 0; k < 4; ++k) v += partials[threadIdx.x * 4 + k];
    for (int off = 32; off > 0; off >>= 1) v += __shfl_xor(v, off);
    if (threadIdx.x == 0) out[0] = (float)v;
}

extern "C" void kernel_launch(void* const* d_in, const int* in_sizes, int n_in,
                              void* d_out, int out_size, void* d_ws, size_t ws_size,
                              hipStream_t stream) {
    const float* vertices = (const float*)d_in[0];
    const float* textures = (const float*)d_in[1];
    const float* image_ref = (const float*)d_in[2];
    const int* faces = (const int*)d_in[3];
    int F = in_sizes[3] / 3;

    // Camera computed on host in f32, mirroring reference _look_at exactly.
    float az = (float)(90.0 * M_PI / 180.0);
    float el = 0.0f;
    float ce = cosf(el), se = sinf(el);
    float sz = sinf(az), cz = cosf(az);
    const float DIST = 2.732f;
    float ex = DIST * (ce * sz);
    float ey = DIST * se;
    float ez = DIST * (-(ce * cz));
    float nrm = sqrtf((ex * ex + ey * ey) + ez * ez);
    float z0 = -ex / nrm, z1 = -ey / nrm, z2 = -ez / nrm;
    float x0 = 1.0f * z2 - 0.0f * z1;
    float x1 = 0.0f * z0 - 0.0f * z2;
    float x2 = 0.0f * z1 - 1.0f * z0;
    float xn = sqrtf((x0 * x0 + x1 * x1) + x2 * x2);
    x0 /= xn; x1 /= xn; x2 /= xn;
    float y0 = z1 * x2 - z2 * x1;
    float y1 = z2 * x0 - z0 * x2;
    float y2 = z0 * x1 - z1 * x0;
    Cam cam{ex, ey, ez, x0, x1, x2, y0, y1, y2, z0, z1, z2};

    double* partials = (double*)d_ws;

    hipLaunchKernelGGL(render_all, dim3(NTILES), dim3(512), 0, stream,
                       vertices, faces, F, cam, textures, image_ref, partials);
    hipLaunchKernelGGL(finalize, dim3(1), dim3(64), 0, stream,
                       partials, (float*)d_out);
}